// Round 10
// baseline (2331.310 us; speedup 1.0000x reference)
//
#include <hip/hip_runtime.h>
#include <math.h>

// ---------------- constants ----------------
#define SEQ 128
#define BATCH 256
#define INPUT 300
#define HIDDEN 1024
#define NG 4096              // 4*HIDDEN, gate-interleaved: n' = 4*j + gate
#define KH 1024
#define KXP 384              // x K padded 300->384 (BK=128 alignment)
#define KT 1408              // KH + KXP (padded; pad region is exact zeros)
#define NKT128 11            // KT/128 k-tiles
#define HT128 8              // KH/128 h k-tiles
#define XT128 3              // KXP/128 x k-tiles
#define NKTH 32              // head k-tiles (K=1024, BK=32)
#define LINEARN 1024
#define AROW 136             // LDS row stride in shorts for BK=128 tiles (128 + 8 pad)
#define TILE_SH (64 * AROW)  // shorts per array (8704)
#define BUF_SH (3 * TILE_SH) // shorts per buffer (26112)
#define HBSTEP (1u << 20)    // 1MB per h step buffer: [hi 512K][lo 512K]

typedef __attribute__((ext_vector_type(8))) short short8;
typedef __attribute__((ext_vector_type(4))) float floatx4;

__device__ __forceinline__ float sigf(float x)     { return 1.f / (1.f + __expf(-x)); }
__device__ __forceinline__ float tanhfast(float x) { return 2.f / (1.f + __expf(-2.f * x)) - 1.f; }

__device__ __forceinline__ unsigned short bf16_rne(float f) {
  unsigned u = __float_as_uint(f);
  u += 0x7FFFu + ((u >> 16) & 1u);
  return (unsigned short)(u >> 16);
}
__device__ __forceinline__ float bf16f(unsigned short s) {
  return __uint_as_float(((unsigned)s) << 16);
}

__device__ __forceinline__ void mfma3(floatx4& acc, short8 ah, short8 al, short8 bh, short8 bl) {
  acc = __builtin_amdgcn_mfma_f32_16x16x32_bf16(ah, bh, acc, 0, 0, 0);
  acc = __builtin_amdgcn_mfma_f32_16x16x32_bf16(ah, bl, acc, 0, 0, 0);
  acc = __builtin_amdgcn_mfma_f32_16x16x32_bf16(al, bh, acc, 0, 0, 0);
}
// W kept at bf16 (hi only); A split hi/lo corrects the h/x quantization.
__device__ __forceinline__ void mfma2(floatx4& acc, short8 ah, short8 al, short8 bh) {
  acc = __builtin_amdgcn_mfma_f32_16x16x32_bf16(ah, bh, acc, 0, 0, 0);
  acc = __builtin_amdgcn_mfma_f32_16x16x32_bf16(al, bh, acc, 0, 0, 0);
}

// ---------------- zero ----------------
__global__ __launch_bounds__(256) void zero_ws(float4* p, int n4) {
  int i = blockIdx.x * 256 + threadIdx.x;
  if (i < n4) p[i] = make_float4(0.f, 0.f, 0.f, 0.f);
}

// ---------------- weight pack: gate-interleave + pad, bf16 hi only ----------------
__global__ __launch_bounds__(256) void pack_w(
    const float* __restrict__ W_ih, const float* __restrict__ W_hh,
    unsigned short* __restrict__ Wph)
{
  int id = blockIdx.x * 256 + threadIdx.x;
  if (id >= NG * KT) return;
  int n = id / KT;
  int k = id - n * KT;
  int j = n >> 2, g = n & 3;
  int srow = g * HIDDEN + j;
  float w = 0.f;
  if (k < KH) w = W_hh[(size_t)srow * HIDDEN + k];
  else if (k - KH < INPUT) w = W_ih[(size_t)srow * INPUT + (k - KH)];
  Wph[id] = bf16_rne(w);
}

__global__ __launch_bounds__(256) void pack_bias(
    const float* __restrict__ b_ih, const float* __restrict__ b_hh,
    float* __restrict__ biasp)
{
  int n = blockIdx.x * 256 + threadIdx.x;
  if (n >= NG) return;
  int j = n >> 2, g = n & 3;
  int s = g * HIDDEN + j;
  biasp[n] = b_ih[s] + b_hh[s];
}

// ---------------- pack all x timesteps to bf16 hi/lo, padded 300->384 ----------------
__global__ __launch_bounds__(256) void pack_x(
    const float* __restrict__ x, unsigned short* __restrict__ xph,
    unsigned short* __restrict__ xpl)
{
  int id = blockIdx.x * 256 + threadIdx.x;
  if (id >= SEQ * BATCH * KXP) return;
  int row = id / KXP;
  int k = id - row * KXP;
  float v = (k < INPUT) ? x[(size_t)row * INPUT + k] : 0.f;
  unsigned short hi = bf16_rne(v);
  xph[id] = hi;
  xpl[id] = bf16_rne(v - bf16f(hi));
}

// ---------------- pack W1 (head) hi/lo ----------------
__global__ __launch_bounds__(256) void pack_w1(
    const float* __restrict__ W1, unsigned short* __restrict__ W1ph,
    unsigned short* __restrict__ W1pl)
{
  int id = blockIdx.x * 256 + threadIdx.x;
  if (id >= LINEARN * HIDDEN) return;
  float w = W1[id];
  unsigned short hi = bf16_rne(w);
  W1ph[id] = hi;
  W1pl[id] = bf16_rne(w - bf16f(hi));
}

// ---------------- persistent LSTM v7: v6 staged body x R5/R6 sync protocol ----------------
// 64 steps per dispatch (phase 0: steps 0..63, phase 1: 64..127). Per step:
//  1. x-part: 3 staged k-tiles (no h dep) -- hides barrier propagation (R5 pattern);
//  2. t0 polls mt-local root (64 blocks = 2 XCDs per m-tile; R5-verified counters);
//  3. h-part: 8 staged k-tiles reading h[st] at a step-unique address (R5-verified
//     freshness: consumer L2 never cached it this dispatch -> plain cached loads OK);
//  4. epilogue: c in regs, h written with PLAIN stores; __syncthreads drains vmcnt;
//     t0: release-agent fence (R6-verified) + relaxed arrive.
// W stays L2-resident per XCD across all 64 steps (1.44 MB < 4 MB) -- no per-step
// L3 re-fetch, no launch gap. Mid-sequence dispatch boundary refreshes L2 so phase 1
// reuses buffers 0..63 (65 x 1MB total); c crosses via cst (boundary-coherent).
__global__ __launch_bounds__(512, 1) void lstm_persist4(
    const unsigned short* __restrict__ xph,   // [SEQ*256][384]
    const unsigned short* __restrict__ xpl,
    const unsigned short* __restrict__ Wph,   // [4096][1408] bf16 hi
    const float* __restrict__ biasp,          // [4096]
    char* __restrict__ hbase,                 // 65 x 1MB step buffers
    unsigned int* barcnt,                     // this phase's region (zeroed)
    float* __restrict__ cst,                  // [256][1024] c handoff between phases
    int phase)
{
  __shared__ short sb[2 * BUF_SH];   // 104448 B
  __shared__ float epi[64 * 65];     // 16640 B

  const int t    = threadIdx.x;
  const int lane = t & 63;
  const int wave = t >> 6;                    // 0..7
  const int wm   = (wave & 3) * 16;           // 1 m-frag
  const int wn   = (wave >> 2) * 32;          // 2 n-frags
  const int col  = lane & 15;
  const int quad = lane >> 4;
  const int r    = t >> 3;                    // staging row 0..63
  const int k8   = (t & 7) * 8;               // staging k offset (shorts)
  const int id   = blockIdx.x;
  const int xcd  = id & 7;
  const int mt_  = xcd >> 1;                  // 2 XCDs per m-tile
  const int jtile = (xcd & 1) * 32 + (id >> 3);
  const int m0 = mt_ * 64, n0 = jtile * 64, j0 = jtile * 16;

  const int mloc = t >> 2;
  const int jl4  = (t & 3) * 4;
  float c4[4] = {0.f, 0.f, 0.f, 0.f};
  if (phase && t < 256) {
    const float4 cv = *(const float4*)(cst + (size_t)(m0 + mloc) * HIDDEN + (j0 + jl4));
    c4[0] = cv.x; c4[1] = cv.y; c4[2] = cv.z; c4[3] = cv.w;
  }

  const float bias0 = biasp[n0 + wn + col];
  const float bias1 = biasp[n0 + wn + 16 + col];
  const int arow  = (wm + col) * AROW + quad * 8;
  const int brow0 = (wn + col) * AROW + quad * 8;
  const int brow1 = (wn + 16 + col) * AROW + quad * 8;

#define LOADX_T(kx, A0_, A1_, L0_, L1_, B0_, B1_) do {                        \
    const int ko = (kx) * 128 + k8;                                           \
    A0_ = *(const uint4*)(xh + (size_t)(m0 + r) * KXP + ko);                  \
    A1_ = *(const uint4*)(xh + (size_t)(m0 + r) * KXP + ko + 64);             \
    L0_ = *(const uint4*)(xl + (size_t)(m0 + r) * KXP + ko);                  \
    L1_ = *(const uint4*)(xl + (size_t)(m0 + r) * KXP + ko + 64);             \
    B0_ = *(const uint4*)(Wph + (size_t)(n0 + r) * KT + KH + ko);             \
    B1_ = *(const uint4*)(Wph + (size_t)(n0 + r) * KT + KH + ko + 64);        \
  } while (0)

#define LOADH_T(kt, A0_, A1_, L0_, L1_, B0_, B1_) do {                        \
    const int ko = (kt) * 128 + k8;                                           \
    A0_ = *(const uint4*)(hrh + (size_t)(m0 + r) * KH + ko);                  \
    A1_ = *(const uint4*)(hrh + (size_t)(m0 + r) * KH + ko + 64);             \
    L0_ = *(const uint4*)(hrl + (size_t)(m0 + r) * KH + ko);                  \
    L1_ = *(const uint4*)(hrl + (size_t)(m0 + r) * KH + ko + 64);             \
    B0_ = *(const uint4*)(Wph + (size_t)(n0 + r) * KT + (kt) * 128 + k8);     \
    B1_ = *(const uint4*)(Wph + (size_t)(n0 + r) * KT + (kt) * 128 + k8 + 64);\
  } while (0)

#define STORE_T(base, A0_, A1_, L0_, L1_, B0_, B1_) do {                      \
    *(uint4*)((base) +               r * AROW + k8)      = A0_;               \
    *(uint4*)((base) +               r * AROW + k8 + 64) = A1_;               \
    *(uint4*)((base) + TILE_SH     + r * AROW + k8)      = L0_;               \
    *(uint4*)((base) + TILE_SH     + r * AROW + k8 + 64) = L1_;               \
    *(uint4*)((base) + 2 * TILE_SH + r * AROW + k8)      = B0_;               \
    *(uint4*)((base) + 2 * TILE_SH + r * AROW + k8 + 64) = B1_;               \
  } while (0)

#define COMPUTE(bufp) do {                                                    \
    _Pragma("unroll")                                                         \
    for (int sub = 0; sub < 4; ++sub) {                                       \
      const int so = sub * 32;                                                \
      const short8 a  = *(const short8*)((bufp) + arow + so);                 \
      const short8 l  = *(const short8*)((bufp) + TILE_SH + arow + so);       \
      const short8 b0 = *(const short8*)((bufp) + 2 * TILE_SH + brow0 + so);  \
      const short8 b1 = *(const short8*)((bufp) + 2 * TILE_SH + brow1 + so);  \
      mfma2(acc[0], a, l, b0);                                                \
      mfma2(acc[1], a, l, b1);                                                \
    } } while (0)

#pragma unroll 1
  for (int s = 0; s < 64; ++s) {
    const int st = phase * 64 + s;
    const unsigned short* xh = xph + (size_t)st * BATCH * KXP;
    const unsigned short* xl = xpl + (size_t)st * BATCH * KXP;
    const int rb = phase ? (s == 0 ? 64 : s - 1) : s;       // read buffer
    const int wb = phase ? s : s + 1;                       // write buffer
    const unsigned short* hrh = (const unsigned short*)(hbase + (size_t)rb * HBSTEP);
    const unsigned short* hrl = hrh + 262144;

    floatx4 acc[2];
    acc[0] = (floatx4){0.f, 0.f, 0.f, 0.f};
    acc[1] = (floatx4){0.f, 0.f, 0.f, 0.f};

    uint4 cA0, cA1, cL0, cL1, cB0, cB1;
    uint4 nA0, nA1, nL0, nL1, nB0, nB1;
    uint4 tA0, tA1, tL0, tL1, tB0, tB1;

    // ---- x-part: 3 staged tiles (no h dependency; runs while barrier propagates) ----
    LOADX_T(0, tA0, tA1, tL0, tL1, tB0, tB1);
    LOADX_T(1, cA0, cA1, cL0, cL1, cB0, cB1);
    STORE_T(sb, tA0, tA1, tL0, tL1, tB0, tB1);
#pragma unroll
    for (int kx = 0; kx < XT128; ++kx) {
      if (kx + 2 < XT128) LOADX_T(kx + 2, nA0, nA1, nL0, nL1, nB0, nB1);
      __syncthreads();
      COMPUTE(sb + (kx & 1) * BUF_SH);
      if (kx + 1 < XT128) STORE_T(sb + ((kx + 1) & 1) * BUF_SH, cA0, cA1, cL0, cL1, cB0, cB1);
      cA0 = nA0; cA1 = nA1; cL0 = nL0; cL1 = nL1; cB0 = nB0; cB1 = nB1;
    }

    // ---- wait for h[st] (mt-local 2-level barrier; skip s=0: buffer pre-ready) ----
    if (s > 0 && t == 0) {
      const unsigned tgt = (unsigned)(s * 2);
      while (__hip_atomic_load(barcnt + mt_ * 32, __ATOMIC_RELAXED,
                               __HIP_MEMORY_SCOPE_AGENT) < tgt)
        __builtin_amdgcn_s_sleep(1);
    }
    __syncthreads();   // broadcast poll; also separates x reads from h tile0 store

    // ---- h-part: 8 staged tiles ----
    LOADH_T(0, tA0, tA1, tL0, tL1, tB0, tB1);
    LOADH_T(1, cA0, cA1, cL0, cL1, cB0, cB1);
    STORE_T(sb, tA0, tA1, tL0, tL1, tB0, tB1);
#pragma unroll
    for (int kt = 0; kt < HT128; ++kt) {
      if (kt + 2 < HT128) LOADH_T(kt + 2, nA0, nA1, nL0, nL1, nB0, nB1);
      __syncthreads();
      COMPUTE(sb + (kt & 1) * BUF_SH);
      if (kt + 1 < HT128) STORE_T(sb + ((kt + 1) & 1) * BUF_SH, cA0, cA1, cL0, cL1, cB0, cB1);
      cA0 = nA0; cA1 = nA1; cL0 = nL0; cL1 = nL1; cB0 = nB0; cB1 = nB1;
    }

    // ---- epilogue: gates -> epi[n'][m] (+bias), fused cell update ----
#pragma unroll
    for (int nt = 0; nt < 2; ++nt) {
      const int nl = wn + nt * 16 + col;
      const float bb = nt ? bias1 : bias0;
#pragma unroll
      for (int reg = 0; reg < 4; ++reg) {
        const int ml = wm + quad * 4 + reg;
        epi[nl * 65 + ml] = acc[nt][reg] + bb;
      }
    }
    __syncthreads();

    unsigned short* hwh = (unsigned short*)(hbase + (size_t)wb * HBSTEP);
    unsigned short* hwl = hwh + 262144;
    if (t < 256) {
      float hn[4];
#pragma unroll
      for (int jj = 0; jj < 4; ++jj) {
        const int nl = (jl4 + jj) * 4;
        const float gi = epi[(nl + 0) * 65 + mloc];
        const float gf = epi[(nl + 1) * 65 + mloc];
        const float gg = epi[(nl + 2) * 65 + mloc];
        const float go = epi[(nl + 3) * 65 + mloc];
        const float cnew = sigf(gf) * c4[jj] + sigf(gi) * tanhfast(gg);
        c4[jj] = cnew;
        hn[jj] = sigf(go) * tanhfast(cnew);
      }
      ushort4 uh, ul;
      uh.x = bf16_rne(hn[0]); uh.y = bf16_rne(hn[1]);
      uh.z = bf16_rne(hn[2]); uh.w = bf16_rne(hn[3]);
      ul.x = bf16_rne(hn[0] - bf16f(uh.x));
      ul.y = bf16_rne(hn[1] - bf16f(uh.y));
      ul.z = bf16_rne(hn[2] - bf16f(uh.z));
      ul.w = bf16_rne(hn[3] - bf16f(uh.w));
      *(ushort4*)(hwh + (size_t)(m0 + mloc) * KH + (j0 + jl4)) = uh;   // plain stores
      *(ushort4*)(hwl + (size_t)(m0 + mloc) * KH + (j0 + jl4)) = ul;
      if (phase == 0 && s == 63)                                        // c handoff
        *(float4*)(cst + (size_t)(m0 + mloc) * HIDDEN + (j0 + jl4)) =
            make_float4(c4[0], c4[1], c4[2], c4[3]);
    }

    __syncthreads();   // drains vmcnt(0): all h stores resident in L2
    if (t == 0) {
      __builtin_amdgcn_fence(__ATOMIC_RELEASE, "agent");   // L2 writeback (R6-verified)
      unsigned* gc = barcnt + 128 + xcd * 32;
      const unsigned old =
          __hip_atomic_fetch_add(gc, 1u, __ATOMIC_RELAXED, __HIP_MEMORY_SCOPE_AGENT);
      if (old == (unsigned)(s * 32 + 31))
        __hip_atomic_fetch_add(barcnt + mt_ * 32, 1u, __ATOMIC_RELAXED,
                               __HIP_MEMORY_SCOPE_AGENT);
    }
    // next iteration's x-part starts immediately (hides barrier propagation)
  }
#undef LOADX_T
#undef LOADH_T
#undef STORE_T
#undef COMPUTE
}

// ---------------- fallback per-step kernel (R9-verified) ----------------
__global__ __launch_bounds__(512) void lstm_step6(
    const unsigned short* __restrict__ xp_hi, const unsigned short* __restrict__ xp_lo,
    const unsigned short* __restrict__ h_hi_r, const unsigned short* __restrict__ h_lo_r,
    const unsigned short* __restrict__ Wph, const float* __restrict__ biasp,
    float* __restrict__ cst, unsigned short* __restrict__ h_hi_w,
    unsigned short* __restrict__ h_lo_w)
{
  __shared__ short sb[2 * BUF_SH];
  __shared__ float epi[64 * 65];

  const int t    = threadIdx.x;
  const int lane = t & 63;
  const int wave = t >> 6;
  const int wm   = (wave & 3) * 16;
  const int wn   = (wave >> 2) * 32;
  const int col  = lane & 15;
  const int quad = lane >> 4;
  const int r    = t >> 3;
  const int k8   = (t & 7) * 8;
  const int id     = blockIdx.x;
  const int jtile  = (id & 7) * 8 + ((id >> 3) & 7);
  const int mt_    = id >> 6;
  const int m0   = mt_ * 64;
  const int n0   = jtile * 64;
  const int j0   = jtile * 16;

  const int mloc = t >> 2;
  const int jl4  = (t & 3) * 4;
  float4 cold;
  if (t < 256) cold = *(const float4*)(cst + (size_t)(m0 + mloc) * HIDDEN + (j0 + jl4));

#define LOAD_TILE(kt, AH0, AH1, AL0, AL1, BH0, BH1) do {                     \
    if ((kt) < HT128) {                                                      \
      const int ka = (kt) * 128 + k8;                                        \
      AH0 = *(const uint4*)(h_hi_r + (size_t)(m0 + r) * KH + ka);            \
      AH1 = *(const uint4*)(h_hi_r + (size_t)(m0 + r) * KH + ka + 64);       \
      AL0 = *(const uint4*)(h_lo_r + (size_t)(m0 + r) * KH + ka);            \
      AL1 = *(const uint4*)(h_lo_r + (size_t)(m0 + r) * KH + ka + 64);       \
    } else {                                                                 \
      const int kx = ((kt) - HT128) * 128 + k8;                              \
      AH0 = *(const uint4*)(xp_hi + (size_t)(m0 + r) * KXP + kx);            \
      AH1 = *(const uint4*)(xp_hi + (size_t)(m0 + r) * KXP + kx + 64);       \
      AL0 = *(const uint4*)(xp_lo + (size_t)(m0 + r) * KXP + kx);            \
      AL1 = *(const uint4*)(xp_lo + (size_t)(m0 + r) * KXP + kx + 64);       \
    }                                                                        \
    BH0 = *(const uint4*)(Wph + (size_t)(n0 + r) * KT + (kt) * 128 + k8);    \
    BH1 = *(const uint4*)(Wph + (size_t)(n0 + r) * KT + (kt) * 128 + k8 + 64);\
  } while (0)

#define STORE_TILE(base, AH0, AH1, AL0, AL1, BH0, BH1) do {                  \
    *(uint4*)((base) +               r * AROW + k8)      = AH0;              \
    *(uint4*)((base) +               r * AROW + k8 + 64) = AH1;              \
    *(uint4*)((base) + TILE_SH     + r * AROW + k8)      = AL0;              \
    *(uint4*)((base) + TILE_SH     + r * AROW + k8 + 64) = AL1;              \
    *(uint4*)((base) + 2 * TILE_SH + r * AROW + k8)      = BH0;              \
    *(uint4*)((base) + 2 * TILE_SH + r * AROW + k8 + 64) = BH1;              \
  } while (0)

  floatx4 acc[2];
  acc[0] = (floatx4){0.f, 0.f, 0.f, 0.f};
  acc[1] = (floatx4){0.f, 0.f, 0.f, 0.f};

  uint4 cA0, cA1, cL0, cL1, cB0, cB1;
  uint4 nA0, nA1, nL0, nL1, nB0, nB1;
  uint4 tA0, tA1, tL0, tL1, tB0, tB1;
  LOAD_TILE(0, tA0, tA1, tL0, tL1, tB0, tB1);
  LOAD_TILE(1, cA0, cA1, cL0, cL1, cB0, cB1);
  STORE_TILE(sb, tA0, tA1, tL0, tL1, tB0, tB1);

  const int arow  = (wm + col) * AROW + quad * 8;
  const int brow0 = (wn + col) * AROW + quad * 8;
  const int brow1 = (wn + 16 + col) * AROW + quad * 8;

  for (int kt = 0; kt < NKT128; ++kt) {
    if (kt + 2 < NKT128) LOAD_TILE(kt + 2, nA0, nA1, nL0, nL1, nB0, nB1);
    __syncthreads();
    const short* bufp = sb + (kt & 1) * BUF_SH;
#pragma unroll
    for (int sub = 0; sub < 4; ++sub) {
      const int so = sub * 32;
      const short8 a  = *(const short8*)(bufp + arow + so);
      const short8 l  = *(const short8*)(bufp + TILE_SH + arow + so);
      const short8 b0 = *(const short8*)(bufp + 2 * TILE_SH + brow0 + so);
      const short8 b1 = *(const short8*)(bufp + 2 * TILE_SH + brow1 + so);
      mfma2(acc[0], a, l, b0);
      mfma2(acc[1], a, l, b1);
    }
    if (kt + 1 < NKT128) STORE_TILE(sb + ((kt + 1) & 1) * BUF_SH, cA0, cA1, cL0, cL1, cB0, cB1);
    cA0 = nA0; cA1 = nA1; cL0 = nL0; cL1 = nL1; cB0 = nB0; cB1 = nB1;
  }
#undef LOAD_TILE
#undef STORE_TILE

  const float bias0 = biasp[n0 + wn + col];
  const float bias1 = biasp[n0 + wn + 16 + col];
#pragma unroll
  for (int nt = 0; nt < 2; ++nt) {
    const int nl = wn + nt * 16 + col;
    const float bb = nt ? bias1 : bias0;
#pragma unroll
    for (int reg = 0; reg < 4; ++reg) {
      const int ml = wm + quad * 4 + reg;
      epi[nl * 65 + ml] = acc[nt][reg] + bb;
    }
  }
  __syncthreads();

  if (t < 256) {
    float cn[4], hn[4];
#pragma unroll
    for (int jj = 0; jj < 4; ++jj) {
      const int nl = (jl4 + jj) * 4;
      const float gi = epi[(nl + 0) * 65 + mloc];
      const float gf = epi[(nl + 1) * 65 + mloc];
      const float gg = epi[(nl + 2) * 65 + mloc];
      const float go = epi[(nl + 3) * 65 + mloc];
      const float cc = (jj == 0) ? cold.x : (jj == 1) ? cold.y : (jj == 2) ? cold.z : cold.w;
      const float cnew = sigf(gf) * cc + sigf(gi) * tanhfast(gg);
      cn[jj] = cnew;
      hn[jj] = sigf(go) * tanhfast(cnew);
    }
    *(float4*)(cst + (size_t)(m0 + mloc) * HIDDEN + (j0 + jl4)) =
        make_float4(cn[0], cn[1], cn[2], cn[3]);
    ushort4 uh, ul;
    uh.x = bf16_rne(hn[0]); uh.y = bf16_rne(hn[1]);
    uh.z = bf16_rne(hn[2]); uh.w = bf16_rne(hn[3]);
    ul.x = bf16_rne(hn[0] - bf16f(uh.x));
    ul.y = bf16_rne(hn[1] - bf16f(uh.y));
    ul.z = bf16_rne(hn[2] - bf16f(uh.z));
    ul.w = bf16_rne(hn[3] - bf16f(uh.w));
    *(ushort4*)(h_hi_w + (size_t)(m0 + mloc) * HIDDEN + (j0 + jl4)) = uh;
    *(ushort4*)(h_lo_w + (size_t)(m0 + mloc) * HIDDEN + (j0 + jl4)) = ul;
  }
}

// ---------------- head GEMM: z = h @ W1^T + b1 (64x64 LDS pipelined, 3-MFMA) ----------------
__global__ __launch_bounds__(256) void head_gemm(
    const unsigned short* __restrict__ Ah_,     // h_hi [256][1024]
    const unsigned short* __restrict__ Al_,
    const unsigned short* __restrict__ Bh_,     // W1 hi [1024][1024]
    const unsigned short* __restrict__ Bl_,
    const float* __restrict__ bias,
    float* __restrict__ C)                      // z [256][1024]
{
  __shared__ short sb[2 * 4 * 2560];

  const int t    = threadIdx.x;
  const int lane = t & 63;
  const int wave = t >> 6;
  const int wm   = (wave >> 1) * 32;
  const int wn   = (wave & 1) * 32;
  const int col  = lane & 15;
  const int quad = lane >> 4;
  const int r    = t >> 2;
  const int k8   = (t & 3) * 8;
  const int m0   = blockIdx.y * 64;
  const int n0   = blockIdx.x * 64;

#define LOAD_TILE(kt, AH, AL, BH, BL) do {                                   \
    const int ka = (kt) * 32 + k8;                                           \
    AH = *(const uint4*)(Ah_ + (size_t)(m0 + r) * KH + ka);                  \
    AL = *(const uint4*)(Al_ + (size_t)(m0 + r) * KH + ka);                  \
    BH = *(const uint4*)(Bh_ + (size_t)(n0 + r) * KH + ka);                  \
    BL = *(const uint4*)(Bl_ + (size_t)(n0 + r) * KH + ka);                  \
  } while (0)

#define STORE_TILE(base, AH, AL, BH, BL) do {                                \
    *(uint4*)((base) +        r * 40 + k8) = AH;                             \
    *(uint4*)((base) + 2560 + r * 40 + k8) = AL;                             \
    *(uint4*)((base) + 5120 + r * 40 + k8) = BH;                             \
    *(uint4*)((base) + 7680 + r * 40 + k8) = BL;                             \
  } while (0)

  floatx4 acc[2][2];
#pragma unroll
  for (int i = 0; i < 2; ++i)
#pragma unroll
    for (int jj = 0; jj < 2; ++jj)
      acc[i][jj] = (floatx4){0.f, 0.f, 0.f, 0.f};

  uint4 cAh, cAl, cBh, cBl, nAh, nAl, nBh, nBl, tAh, tAl, tBh, tBl;
  LOAD_TILE(0, tAh, tAl, tBh, tBl);
  LOAD_TILE(1, cAh, cAl, cBh, cBl);
  STORE_TILE(sb, tAh, tAl, tBh, tBl);

  for (int kt = 0; kt < NKTH; ++kt) {
    if (kt + 2 < NKTH) LOAD_TILE(kt + 2, nAh, nAl, nBh, nBl);
    __syncthreads();
    short* bufp = sb + (kt & 1) * 10240;

    short8 ah[2], al[2], bh[2], bl[2];
#pragma unroll
    for (int mt = 0; mt < 2; ++mt) {
      const int row = (wm + mt * 16 + col) * 40 + quad * 8;
      ah[mt] = *(const short8*)(bufp + row);
      al[mt] = *(const short8*)(bufp + 2560 + row);
    }
#pragma unroll
    for (int nt = 0; nt < 2; ++nt) {
      const int row = (wn + nt * 16 + col) * 40 + quad * 8;
      bh[nt] = *(const short8*)(bufp + 5120 + row);
      bl[nt] = *(const short8*)(bufp + 7680 + row);
    }
#pragma unroll
    for (int mt = 0; mt < 2; ++mt)
#pragma unroll
      for (int nt = 0; nt < 2; ++nt)
        mfma3(acc[mt][nt], ah[mt], al[mt], bh[nt], bl[nt]);

    if (kt + 1 < NKTH) STORE_TILE(sb + ((kt + 1) & 1) * 10240, cAh, cAl, cBh, cBl);
    cAh = nAh; cAl = nAl; cBh = nBh; cBl = nBl;
  }
#undef LOAD_TILE
#undef STORE_TILE

#pragma unroll
  for (int mt = 0; mt < 2; ++mt)
#pragma unroll
    for (int nt = 0; nt < 2; ++nt) {
      const int nl = n0 + wn + nt * 16 + col;
      const float bb = bias[nl];
#pragma unroll
      for (int reg = 0; reg < 4; ++reg) {
        const int ml = m0 + wm + mt * 16 + quad * 4 + reg;
        C[(size_t)ml * LINEARN + nl] = acc[mt][nt][reg] + bb;
      }
    }
}

// ---------------- BN stats ----------------
__global__ __launch_bounds__(64) void bn_stats(
    const float* __restrict__ z, float* __restrict__ mean, float* __restrict__ rstd)
{
  const int n = blockIdx.x;
  const int t = threadIdx.x;
  float s = 0.f, s2 = 0.f;
  for (int r = t; r < BATCH; r += 64) {
    const float v = z[(size_t)r * LINEARN + n];
    s += v; s2 += v * v;
  }
#pragma unroll
  for (int off = 32; off > 0; off >>= 1) {
    s  += __shfl_down(s,  off, 64);
    s2 += __shfl_down(s2, off, 64);
  }
  if (t == 0) {
    const float mm = s * (1.f / BATCH);
    mean[n] = mm;
    rstd[n] = rsqrtf(s2 * (1.f / BATCH) - mm * mm + 1e-5f);
  }
}

// ---------------- head out ----------------
__global__ __launch_bounds__(256) void head_out(
    const float* __restrict__ z, const float* __restrict__ mean, const float* __restrict__ rstd,
    const float* __restrict__ gamma, const float* __restrict__ beta,
    const float* __restrict__ W2, const float* __restrict__ b2, float* __restrict__ out)
{
  const int b = blockIdx.x;
  const int t = threadIdx.x;
  float acc = 0.f;
  for (int n = t; n < LINEARN; n += 256) {
    float v = (z[(size_t)b * LINEARN + n] - mean[n]) * rstd[n] * gamma[n] + beta[n];
    v = fmaxf(v, 0.f);
    acc += v * W2[n];
  }
#pragma unroll
  for (int off = 32; off > 0; off >>= 1) acc += __shfl_down(acc, off, 64);
  __shared__ float ls[4];
  if ((t & 63) == 0) ls[t >> 6] = acc;
  __syncthreads();
  if (t == 0) {
    const float tot = ls[0] + ls[1] + ls[2] + ls[3] + b2[0];
    out[b] = 3.f / (1.f + __expf(-tot));
  }
}

// ---------------- launch ----------------
extern "C" void kernel_launch(void* const* d_in, const int* in_sizes, int n_in,
                              void* d_out, int out_size, void* d_ws, size_t ws_size,
                              hipStream_t stream) {
  const float* x     = (const float*)d_in[0];
  const float* W_ih  = (const float*)d_in[1];
  const float* W_hh  = (const float*)d_in[2];
  const float* b_ih  = (const float*)d_in[3];
  const float* b_hh  = (const float*)d_in[4];
  const float* W1    = (const float*)d_in[5];
  const float* b1    = (const float*)d_in[6];
  const float* gamma = (const float*)d_in[7];
  const float* beta  = (const float*)d_in[8];
  const float* W2    = (const float*)d_in[9];
  const float* b2    = (const float*)d_in[10];
  float* out = (float*)d_out;
  char* w = (char*)d_ws;

  // persistent-path layout
  const size_t HB_OFF   = 0;                     // 65 x 1MB = 68,157,440
  const size_t BARC_OFF = 68157440;              // 8 KB (two 4KB phase regions)
  const size_t CST_OFF  = 68165632;              // 1 MB
  const size_t WPH_OFF  = 69214208;              // 11,534,336
  const size_t BIAS_OFF = 80748544;              // 16 KB
  const size_t XPH_OFF  = 80764928;              // 25,165,824
  const size_t XPL_OFF  = 105930752;             // 25,165,824
  const size_t W1PH_OFF = 131096576;             // 2 MB
  const size_t W1PL_OFF = 133193728;             // 2 MB
  const size_t Z_OFF    = 135290880;             // 1 MB
  const size_t MEAN_OFF = 136339456;
  const size_t RSTD_OFF = 136343552;
  const size_t NEED     = 136347648;

  if (ws_size >= NEED) {
    unsigned short* Wph   = (unsigned short*)(w + WPH_OFF);
    float*          biasp = (float*)(w + BIAS_OFF);
    unsigned short* xph   = (unsigned short*)(w + XPH_OFF);
    unsigned short* xpl   = (unsigned short*)(w + XPL_OFF);
    unsigned short* W1ph  = (unsigned short*)(w + W1PH_OFF);
    unsigned short* W1pl  = (unsigned short*)(w + W1PL_OFF);
    float*          cst   = (float*)(w + CST_OFF);
    float*          z     = (float*)(w + Z_OFF);
    float*          mean  = (float*)(w + MEAN_OFF);
    float*          rstd  = (float*)(w + RSTD_OFF);
    unsigned int*   barcA = (unsigned int*)(w + BARC_OFF);
    unsigned int*   barcB = barcA + 1024;

    zero_ws<<<256, 256, 0, stream>>>((float4*)(w + HB_OFF), 65536);   // h[0] = 0
    zero_ws<<<2, 256, 0, stream>>>((float4*)(w + BARC_OFF), 512);     // both barrier regions
    pack_w<<<(NG * KT + 255) / 256, 256, 0, stream>>>(W_ih, W_hh, Wph);
    pack_bias<<<NG / 256, 256, 0, stream>>>(b_ih, b_hh, biasp);
    pack_x<<<(SEQ * BATCH * KXP + 255) / 256, 256, 0, stream>>>(x, xph, xpl);
    pack_w1<<<(LINEARN * HIDDEN + 255) / 256, 256, 0, stream>>>(W1, W1ph, W1pl);

    lstm_persist4<<<256, 512, 0, stream>>>(xph, xpl, Wph, biasp, w + HB_OFF, barcA, cst, 0);
    lstm_persist4<<<256, 512, 0, stream>>>(xph, xpl, Wph, biasp, w + HB_OFF, barcB, cst, 1);

    // final h (global step 128) = phase-1 local s=63 -> buffer 63
    const unsigned short* hfh = (const unsigned short*)(w + HB_OFF + (size_t)63 * HBSTEP);
    const unsigned short* hfl = hfh + 262144;
    head_gemm<<<dim3(LINEARN / 64, BATCH / 64), 256, 0, stream>>>(
        hfh, hfl, W1ph, W1pl, b1, z);
    bn_stats<<<LINEARN, 64, 0, stream>>>(z, mean, rstd);
    head_out<<<BATCH, 256, 0, stream>>>(z, mean, rstd, gamma, beta, W2, b2, out);
  } else {
    // -------- fallback: R9-verified 128-launch path --------
    unsigned short* h_hi0 = (unsigned short*)(w + 0);
    unsigned short* h_lo0 = (unsigned short*)(w + 524288);
    float*          cst   = (float*)(w + 1048576);
    unsigned short* h_hi1 = (unsigned short*)(w + 2097152);
    unsigned short* h_lo1 = (unsigned short*)(w + 2621440);
    unsigned short* Wph   = (unsigned short*)(w + 3145728);
    float*          biasp = (float*)(w + 14680064);
    unsigned short* xph   = (unsigned short*)(w + 14696448);
    unsigned short* xpl   = (unsigned short*)(w + 39862272);
    unsigned short* W1ph  = (unsigned short*)(w + 65028096);
    unsigned short* W1pl  = (unsigned short*)(w + 67125248);
    float*          z     = (float*)(w + 69222400);
    float*          mean  = (float*)(w + 70270976);
    float*          rstd  = (float*)(w + 70275072);

    zero_ws<<<512, 256, 0, stream>>>((float4*)w, 131072);
    pack_w<<<(NG * KT + 255) / 256, 256, 0, stream>>>(W_ih, W_hh, Wph);
    pack_bias<<<NG / 256, 256, 0, stream>>>(b_ih, b_hh, biasp);
    pack_x<<<(SEQ * BATCH * KXP + 255) / 256, 256, 0, stream>>>(x, xph, xpl);
    pack_w1<<<(LINEARN * HIDDEN + 255) / 256, 256, 0, stream>>>(W1, W1ph, W1pl);

    for (int t = 0; t < SEQ; ++t) {
      const unsigned short* hr_hi = (t & 1) ? h_hi1 : h_hi0;
      const unsigned short* hr_lo = (t & 1) ? h_lo1 : h_lo0;
      unsigned short* hw_hi = (t & 1) ? h_hi0 : h_hi1;
      unsigned short* hw_lo = (t & 1) ? h_lo0 : h_lo1;
      lstm_step6<<<256, 512, 0, stream>>>(
          xph + (size_t)t * BATCH * KXP, xpl + (size_t)t * BATCH * KXP,
          hr_hi, hr_lo, Wph, biasp, cst, hw_hi, hw_lo);
    }
    head_gemm<<<dim3(LINEARN / 64, BATCH / 64), 256, 0, stream>>>(
        h_hi0, h_lo0, W1ph, W1pl, b1, z);
    bn_stats<<<LINEARN, 64, 0, stream>>>(z, mean, rstd);
    head_out<<<BATCH, 256, 0, stream>>>(z, mean, rstd, gamma, beta, W2, b2, out);
  }
}

// Round 11
// 1518.379 us; speedup vs baseline: 1.5354x; 1.5354x over previous
//
#include <hip/hip_runtime.h>
#include <math.h>

// ---------------- constants ----------------
#define SEQ 128
#define BATCH 256
#define INPUT 300
#define HIDDEN 1024
#define NG 4096              // 4*HIDDEN, gate-interleaved: n' = 4*j + gate
#define KH 1024
#define KXP 384              // x K padded 300->384 (BK=128 alignment)
#define KT 1408              // KH + KXP (padded; pad region is exact zeros)
#define NKT128 11            // KT/128 k-tiles
#define HT128 8              // KH/128 h k-tiles
#define XT128 3              // KXP/128 x k-tiles
#define NKTH 32              // head k-tiles (K=1024, BK=32)
#define LINEARN 1024
#define AROW 168             // LDS row stride in shorts: 84 dwords = 20 mod 32 (R0's proven residue)
#define TILE_SH (64 * AROW)  // shorts per array (10752)
#define BUF_SH (3 * TILE_SH) // shorts per buffer (32256)
#define HBSTEP (1u << 20)    // 1MB per h step buffer: [hi 512K][lo 512K]

typedef __attribute__((ext_vector_type(8))) short short8;
typedef __attribute__((ext_vector_type(4))) float floatx4;

__device__ __forceinline__ float sigf(float x)     { return 1.f / (1.f + __expf(-x)); }
__device__ __forceinline__ float tanhfast(float x) { return 2.f / (1.f + __expf(-2.f * x)) - 1.f; }

__device__ __forceinline__ unsigned short bf16_rne(float f) {
  unsigned u = __float_as_uint(f);
  u += 0x7FFFu + ((u >> 16) & 1u);
  return (unsigned short)(u >> 16);
}
__device__ __forceinline__ float bf16f(unsigned short s) {
  return __uint_as_float(((unsigned)s) << 16);
}

__device__ __forceinline__ void mfma3(floatx4& acc, short8 ah, short8 al, short8 bh, short8 bl) {
  acc = __builtin_amdgcn_mfma_f32_16x16x32_bf16(ah, bh, acc, 0, 0, 0);
  acc = __builtin_amdgcn_mfma_f32_16x16x32_bf16(ah, bl, acc, 0, 0, 0);
  acc = __builtin_amdgcn_mfma_f32_16x16x32_bf16(al, bh, acc, 0, 0, 0);
}
// W kept at bf16 (hi only); A split hi/lo corrects the h/x quantization.
__device__ __forceinline__ void mfma2(floatx4& acc, short8 ah, short8 al, short8 bh) {
  acc = __builtin_amdgcn_mfma_f32_16x16x32_bf16(ah, bh, acc, 0, 0, 0);
  acc = __builtin_amdgcn_mfma_f32_16x16x32_bf16(al, bh, acc, 0, 0, 0);
}

// ---------------- zero ----------------
__global__ __launch_bounds__(256) void zero_ws(float4* p, int n4) {
  int i = blockIdx.x * 256 + threadIdx.x;
  if (i < n4) p[i] = make_float4(0.f, 0.f, 0.f, 0.f);
}

// ---------------- weight pack: gate-interleave + pad, bf16 hi only ----------------
__global__ __launch_bounds__(256) void pack_w(
    const float* __restrict__ W_ih, const float* __restrict__ W_hh,
    unsigned short* __restrict__ Wph)
{
  int id = blockIdx.x * 256 + threadIdx.x;
  if (id >= NG * KT) return;
  int n = id / KT;
  int k = id - n * KT;
  int j = n >> 2, g = n & 3;
  int srow = g * HIDDEN + j;
  float w = 0.f;
  if (k < KH) w = W_hh[(size_t)srow * HIDDEN + k];
  else if (k - KH < INPUT) w = W_ih[(size_t)srow * INPUT + (k - KH)];
  Wph[id] = bf16_rne(w);
}

__global__ __launch_bounds__(256) void pack_bias(
    const float* __restrict__ b_ih, const float* __restrict__ b_hh,
    float* __restrict__ biasp)
{
  int n = blockIdx.x * 256 + threadIdx.x;
  if (n >= NG) return;
  int j = n >> 2, g = n & 3;
  int s = g * HIDDEN + j;
  biasp[n] = b_ih[s] + b_hh[s];
}

// ---------------- pack all x timesteps to bf16 hi/lo, padded 300->384 ----------------
__global__ __launch_bounds__(256) void pack_x(
    const float* __restrict__ x, unsigned short* __restrict__ xph,
    unsigned short* __restrict__ xpl)
{
  int id = blockIdx.x * 256 + threadIdx.x;
  if (id >= SEQ * BATCH * KXP) return;
  int row = id / KXP;
  int k = id - row * KXP;
  float v = (k < INPUT) ? x[(size_t)row * INPUT + k] : 0.f;
  unsigned short hi = bf16_rne(v);
  xph[id] = hi;
  xpl[id] = bf16_rne(v - bf16f(hi));
}

// ---------------- pack W1 (head) hi/lo ----------------
__global__ __launch_bounds__(256) void pack_w1(
    const float* __restrict__ W1, unsigned short* __restrict__ W1ph,
    unsigned short* __restrict__ W1pl)
{
  int id = blockIdx.x * 256 + threadIdx.x;
  if (id >= LINEARN * HIDDEN) return;
  float w = W1[id];
  unsigned short hi = bf16_rne(w);
  W1ph[id] = hi;
  W1pl[id] = bf16_rne(w - bf16f(hi));
}

// ---------------- persistent LSTM v8: v7 + 1-wbl2-per-XCD sync + conflict-free AROW ----
// R10 counters: W stayed L2-resident (FETCH 1.76 MB/step) but sync cost ~8us/step --
// 32 release fences (buffer_wbl2) per XCD per step serialized in TCC. v8: only the
// LAST arriver of each XCD's 32 blocks issues the fence (wbl2 is a cache op on the
// shared XCD L2 -- it flushes ALL 32 blocks' h stores, which are L2-resident by
// their pre-arrive __syncthreads vmcnt drain; RMW visibility implies drain done).
// Also AROW 136->168 (84 dwords = 20 mod 32): b128 staging/read start-banks spread
// (R10's 9.6e7 SQ_LDS_BANK_CONFLICT came from 68 = 4 mod 32 collapsing to 8 groups).
__global__ __launch_bounds__(512, 1) void lstm_persist4(
    const unsigned short* __restrict__ xph,   // [SEQ*256][384]
    const unsigned short* __restrict__ xpl,
    const unsigned short* __restrict__ Wph,   // [4096][1408] bf16 hi
    const float* __restrict__ biasp,          // [4096]
    char* __restrict__ hbase,                 // 65 x 1MB step buffers
    unsigned int* barcnt,                     // this phase's region (zeroed)
    float* __restrict__ cst,                  // [256][1024] c handoff between phases
    int phase)
{
  __shared__ short sb[2 * BUF_SH];   // 129024 B
  __shared__ float epi[64 * 65];     // 16640 B (145664 total, 1 block/CU)

  const int t    = threadIdx.x;
  const int lane = t & 63;
  const int wave = t >> 6;                    // 0..7
  const int wm   = (wave & 3) * 16;           // 1 m-frag
  const int wn   = (wave >> 2) * 32;          // 2 n-frags
  const int col  = lane & 15;
  const int quad = lane >> 4;
  const int r    = t >> 3;                    // staging row 0..63
  const int k8   = (t & 7) * 8;               // staging k offset (shorts)
  const int id   = blockIdx.x;
  const int xcd  = id & 7;
  const int mt_  = xcd >> 1;                  // 2 XCDs per m-tile
  const int jtile = (xcd & 1) * 32 + (id >> 3);
  const int m0 = mt_ * 64, n0 = jtile * 64, j0 = jtile * 16;

  const int mloc = t >> 2;
  const int jl4  = (t & 3) * 4;
  float c4[4] = {0.f, 0.f, 0.f, 0.f};
  if (phase && t < 256) {
    const float4 cv = *(const float4*)(cst + (size_t)(m0 + mloc) * HIDDEN + (j0 + jl4));
    c4[0] = cv.x; c4[1] = cv.y; c4[2] = cv.z; c4[3] = cv.w;
  }

  const float bias0 = biasp[n0 + wn + col];
  const float bias1 = biasp[n0 + wn + 16 + col];
  const int arow  = (wm + col) * AROW + quad * 8;
  const int brow0 = (wn + col) * AROW + quad * 8;
  const int brow1 = (wn + 16 + col) * AROW + quad * 8;

#define LOADX_T(kx, A0_, A1_, L0_, L1_, B0_, B1_) do {                        \
    const int ko = (kx) * 128 + k8;                                           \
    A0_ = *(const uint4*)(xh + (size_t)(m0 + r) * KXP + ko);                  \
    A1_ = *(const uint4*)(xh + (size_t)(m0 + r) * KXP + ko + 64);             \
    L0_ = *(const uint4*)(xl + (size_t)(m0 + r) * KXP + ko);                  \
    L1_ = *(const uint4*)(xl + (size_t)(m0 + r) * KXP + ko + 64);             \
    B0_ = *(const uint4*)(Wph + (size_t)(n0 + r) * KT + KH + ko);             \
    B1_ = *(const uint4*)(Wph + (size_t)(n0 + r) * KT + KH + ko + 64);        \
  } while (0)

#define LOADH_T(kt, A0_, A1_, L0_, L1_, B0_, B1_) do {                        \
    const int ko = (kt) * 128 + k8;                                           \
    A0_ = *(const uint4*)(hrh + (size_t)(m0 + r) * KH + ko);                  \
    A1_ = *(const uint4*)(hrh + (size_t)(m0 + r) * KH + ko + 64);             \
    L0_ = *(const uint4*)(hrl + (size_t)(m0 + r) * KH + ko);                  \
    L1_ = *(const uint4*)(hrl + (size_t)(m0 + r) * KH + ko + 64);             \
    B0_ = *(const uint4*)(Wph + (size_t)(n0 + r) * KT + (kt) * 128 + k8);     \
    B1_ = *(const uint4*)(Wph + (size_t)(n0 + r) * KT + (kt) * 128 + k8 + 64);\
  } while (0)

#define STORE_T(base, A0_, A1_, L0_, L1_, B0_, B1_) do {                      \
    *(uint4*)((base) +               r * AROW + k8)      = A0_;               \
    *(uint4*)((base) +               r * AROW + k8 + 64) = A1_;               \
    *(uint4*)((base) + TILE_SH     + r * AROW + k8)      = L0_;               \
    *(uint4*)((base) + TILE_SH     + r * AROW + k8 + 64) = L1_;               \
    *(uint4*)((base) + 2 * TILE_SH + r * AROW + k8)      = B0_;               \
    *(uint4*)((base) + 2 * TILE_SH + r * AROW + k8 + 64) = B1_;               \
  } while (0)

#define COMPUTE(bufp) do {                                                    \
    _Pragma("unroll")                                                         \
    for (int sub = 0; sub < 4; ++sub) {                                       \
      const int so = sub * 32;                                                \
      const short8 a  = *(const short8*)((bufp) + arow + so);                 \
      const short8 l  = *(const short8*)((bufp) + TILE_SH + arow + so);       \
      const short8 b0 = *(const short8*)((bufp) + 2 * TILE_SH + brow0 + so);  \
      const short8 b1 = *(const short8*)((bufp) + 2 * TILE_SH + brow1 + so);  \
      mfma2(acc[0], a, l, b0);                                                \
      mfma2(acc[1], a, l, b1);                                                \
    } } while (0)

#pragma unroll 1
  for (int s = 0; s < 64; ++s) {
    const int st = phase * 64 + s;
    const unsigned short* xh = xph + (size_t)st * BATCH * KXP;
    const unsigned short* xl = xpl + (size_t)st * BATCH * KXP;
    const int rb = phase ? (s == 0 ? 64 : s - 1) : s;       // read buffer
    const int wb = phase ? s : s + 1;                       // write buffer
    const unsigned short* hrh = (const unsigned short*)(hbase + (size_t)rb * HBSTEP);
    const unsigned short* hrl = hrh + 262144;

    floatx4 acc[2];
    acc[0] = (floatx4){0.f, 0.f, 0.f, 0.f};
    acc[1] = (floatx4){0.f, 0.f, 0.f, 0.f};

    uint4 cA0, cA1, cL0, cL1, cB0, cB1;
    uint4 nA0, nA1, nL0, nL1, nB0, nB1;
    uint4 tA0, tA1, tL0, tL1, tB0, tB1;

    // ---- x-part: 3 staged tiles (no h dependency; runs while barrier propagates) ----
    LOADX_T(0, tA0, tA1, tL0, tL1, tB0, tB1);
    LOADX_T(1, cA0, cA1, cL0, cL1, cB0, cB1);
    STORE_T(sb, tA0, tA1, tL0, tL1, tB0, tB1);
#pragma unroll
    for (int kx = 0; kx < XT128; ++kx) {
      if (kx + 2 < XT128) LOADX_T(kx + 2, nA0, nA1, nL0, nL1, nB0, nB1);
      __syncthreads();
      COMPUTE(sb + (kx & 1) * BUF_SH);
      if (kx + 1 < XT128) STORE_T(sb + ((kx + 1) & 1) * BUF_SH, cA0, cA1, cL0, cL1, cB0, cB1);
      cA0 = nA0; cA1 = nA1; cL0 = nL0; cL1 = nL1; cB0 = nB0; cB1 = nB1;
    }

    // ---- wait for h[st] (mt-local 2-level barrier; skip s=0: buffer pre-ready) ----
    if (s > 0 && t == 0) {
      const unsigned tgt = (unsigned)(s * 2);
      while (__hip_atomic_load(barcnt + mt_ * 32, __ATOMIC_RELAXED,
                               __HIP_MEMORY_SCOPE_AGENT) < tgt)
        __builtin_amdgcn_s_sleep(1);
    }
    __syncthreads();   // broadcast poll; also separates x reads from h tile0 store

    // ---- h-part: 8 staged tiles ----
    LOADH_T(0, tA0, tA1, tL0, tL1, tB0, tB1);
    LOADH_T(1, cA0, cA1, cL0, cL1, cB0, cB1);
    STORE_T(sb, tA0, tA1, tL0, tL1, tB0, tB1);
#pragma unroll
    for (int kt = 0; kt < HT128; ++kt) {
      if (kt + 2 < HT128) LOADH_T(kt + 2, nA0, nA1, nL0, nL1, nB0, nB1);
      __syncthreads();
      COMPUTE(sb + (kt & 1) * BUF_SH);
      if (kt + 1 < HT128) STORE_T(sb + ((kt + 1) & 1) * BUF_SH, cA0, cA1, cL0, cL1, cB0, cB1);
      cA0 = nA0; cA1 = nA1; cL0 = nL0; cL1 = nL1; cB0 = nB0; cB1 = nB1;
    }

    // ---- epilogue: gates -> epi[n'][m] (+bias), fused cell update ----
#pragma unroll
    for (int nt = 0; nt < 2; ++nt) {
      const int nl = wn + nt * 16 + col;
      const float bb = nt ? bias1 : bias0;
#pragma unroll
      for (int reg = 0; reg < 4; ++reg) {
        const int ml = wm + quad * 4 + reg;
        epi[nl * 65 + ml] = acc[nt][reg] + bb;
      }
    }
    __syncthreads();

    unsigned short* hwh = (unsigned short*)(hbase + (size_t)wb * HBSTEP);
    unsigned short* hwl = hwh + 262144;
    if (t < 256) {
      float hn[4];
#pragma unroll
      for (int jj = 0; jj < 4; ++jj) {
        const int nl = (jl4 + jj) * 4;
        const float gi = epi[(nl + 0) * 65 + mloc];
        const float gf = epi[(nl + 1) * 65 + mloc];
        const float gg = epi[(nl + 2) * 65 + mloc];
        const float go = epi[(nl + 3) * 65 + mloc];
        const float cnew = sigf(gf) * c4[jj] + sigf(gi) * tanhfast(gg);
        c4[jj] = cnew;
        hn[jj] = sigf(go) * tanhfast(cnew);
      }
      ushort4 uh, ul;
      uh.x = bf16_rne(hn[0]); uh.y = bf16_rne(hn[1]);
      uh.z = bf16_rne(hn[2]); uh.w = bf16_rne(hn[3]);
      ul.x = bf16_rne(hn[0] - bf16f(uh.x));
      ul.y = bf16_rne(hn[1] - bf16f(uh.y));
      ul.z = bf16_rne(hn[2] - bf16f(uh.z));
      ul.w = bf16_rne(hn[3] - bf16f(uh.w));
      *(ushort4*)(hwh + (size_t)(m0 + mloc) * KH + (j0 + jl4)) = uh;   // plain stores
      *(ushort4*)(hwl + (size_t)(m0 + mloc) * KH + (j0 + jl4)) = ul;
      if (phase == 0 && s == 63)                                        // c handoff
        *(float4*)(cst + (size_t)(m0 + mloc) * HIDDEN + (j0 + jl4)) =
            make_float4(c4[0], c4[1], c4[2], c4[3]);
    }

    __syncthreads();   // drains vmcnt(0): this block's h stores resident in XCD L2
    if (t == 0) {
      unsigned* gc = barcnt + 128 + xcd * 32;
      const unsigned old =
          __hip_atomic_fetch_add(gc, 1u, __ATOMIC_RELAXED, __HIP_MEMORY_SCOPE_AGENT);
      if (old == (unsigned)(s * 32 + 31)) {
        // LAST arriver of this XCD: all 32 blocks' h stores are in this L2
        // (their RMW visibility implies their vmcnt drains completed).
        // ONE wbl2 flushes them all to the coherence point, then publish.
        __builtin_amdgcn_fence(__ATOMIC_RELEASE, "agent");
        __hip_atomic_fetch_add(barcnt + mt_ * 32, 1u, __ATOMIC_RELAXED,
                               __HIP_MEMORY_SCOPE_AGENT);
      }
    }
    // next iteration's x-part starts immediately (hides barrier propagation)
  }
#undef LOADX_T
#undef LOADH_T
#undef STORE_T
#undef COMPUTE
}

// ---------------- fallback per-step kernel (R9-verified) ----------------
__global__ __launch_bounds__(512) void lstm_step6(
    const unsigned short* __restrict__ xp_hi, const unsigned short* __restrict__ xp_lo,
    const unsigned short* __restrict__ h_hi_r, const unsigned short* __restrict__ h_lo_r,
    const unsigned short* __restrict__ Wph, const float* __restrict__ biasp,
    float* __restrict__ cst, unsigned short* __restrict__ h_hi_w,
    unsigned short* __restrict__ h_lo_w)
{
  __shared__ short sb[2 * BUF_SH];
  __shared__ float epi[64 * 65];

  const int t    = threadIdx.x;
  const int lane = t & 63;
  const int wave = t >> 6;
  const int wm   = (wave & 3) * 16;
  const int wn   = (wave >> 2) * 32;
  const int col  = lane & 15;
  const int quad = lane >> 4;
  const int r    = t >> 3;
  const int k8   = (t & 7) * 8;
  const int id     = blockIdx.x;
  const int jtile  = (id & 7) * 8 + ((id >> 3) & 7);
  const int mt_    = id >> 6;
  const int m0   = mt_ * 64;
  const int n0   = jtile * 64;
  const int j0   = jtile * 16;

  const int mloc = t >> 2;
  const int jl4  = (t & 3) * 4;
  float4 cold;
  if (t < 256) cold = *(const float4*)(cst + (size_t)(m0 + mloc) * HIDDEN + (j0 + jl4));

#define LOAD_TILE(kt, AH0, AH1, AL0, AL1, BH0, BH1) do {                     \
    if ((kt) < HT128) {                                                      \
      const int ka = (kt) * 128 + k8;                                        \
      AH0 = *(const uint4*)(h_hi_r + (size_t)(m0 + r) * KH + ka);            \
      AH1 = *(const uint4*)(h_hi_r + (size_t)(m0 + r) * KH + ka + 64);       \
      AL0 = *(const uint4*)(h_lo_r + (size_t)(m0 + r) * KH + ka);            \
      AL1 = *(const uint4*)(h_lo_r + (size_t)(m0 + r) * KH + ka + 64);       \
    } else {                                                                 \
      const int kx = ((kt) - HT128) * 128 + k8;                              \
      AH0 = *(const uint4*)(xp_hi + (size_t)(m0 + r) * KXP + kx);            \
      AH1 = *(const uint4*)(xp_hi + (size_t)(m0 + r) * KXP + kx + 64);       \
      AL0 = *(const uint4*)(xp_lo + (size_t)(m0 + r) * KXP + kx);            \
      AL1 = *(const uint4*)(xp_lo + (size_t)(m0 + r) * KXP + kx + 64);       \
    }                                                                        \
    BH0 = *(const uint4*)(Wph + (size_t)(n0 + r) * KT + (kt) * 128 + k8);    \
    BH1 = *(const uint4*)(Wph + (size_t)(n0 + r) * KT + (kt) * 128 + k8 + 64);\
  } while (0)

#define STORE_TILE(base, AH0, AH1, AL0, AL1, BH0, BH1) do {                  \
    *(uint4*)((base) +               r * AROW + k8)      = AH0;              \
    *(uint4*)((base) +               r * AROW + k8 + 64) = AH1;              \
    *(uint4*)((base) + TILE_SH     + r * AROW + k8)      = AL0;              \
    *(uint4*)((base) + TILE_SH     + r * AROW + k8 + 64) = AL1;              \
    *(uint4*)((base) + 2 * TILE_SH + r * AROW + k8)      = BH0;              \
    *(uint4*)((base) + 2 * TILE_SH + r * AROW + k8 + 64) = BH1;              \
  } while (0)

  floatx4 acc[2];
  acc[0] = (floatx4){0.f, 0.f, 0.f, 0.f};
  acc[1] = (floatx4){0.f, 0.f, 0.f, 0.f};

  uint4 cA0, cA1, cL0, cL1, cB0, cB1;
  uint4 nA0, nA1, nL0, nL1, nB0, nB1;
  uint4 tA0, tA1, tL0, tL1, tB0, tB1;
  LOAD_TILE(0, tA0, tA1, tL0, tL1, tB0, tB1);
  LOAD_TILE(1, cA0, cA1, cL0, cL1, cB0, cB1);
  STORE_TILE(sb, tA0, tA1, tL0, tL1, tB0, tB1);

  const int arow  = (wm + col) * AROW + quad * 8;
  const int brow0 = (wn + col) * AROW + quad * 8;
  const int brow1 = (wn + 16 + col) * AROW + quad * 8;

  for (int kt = 0; kt < NKT128; ++kt) {
    if (kt + 2 < NKT128) LOAD_TILE(kt + 2, nA0, nA1, nL0, nL1, nB0, nB1);
    __syncthreads();
    const short* bufp = sb + (kt & 1) * BUF_SH;
#pragma unroll
    for (int sub = 0; sub < 4; ++sub) {
      const int so = sub * 32;
      const short8 a  = *(const short8*)(bufp + arow + so);
      const short8 l  = *(const short8*)(bufp + TILE_SH + arow + so);
      const short8 b0 = *(const short8*)(bufp + 2 * TILE_SH + brow0 + so);
      const short8 b1 = *(const short8*)(bufp + 2 * TILE_SH + brow1 + so);
      mfma2(acc[0], a, l, b0);
      mfma2(acc[1], a, l, b1);
    }
    if (kt + 1 < NKT128) STORE_TILE(sb + ((kt + 1) & 1) * BUF_SH, cA0, cA1, cL0, cL1, cB0, cB1);
    cA0 = nA0; cA1 = nA1; cL0 = nL0; cL1 = nL1; cB0 = nB0; cB1 = nB1;
  }
#undef LOAD_TILE
#undef STORE_TILE

  const float bias0 = biasp[n0 + wn + col];
  const float bias1 = biasp[n0 + wn + 16 + col];
#pragma unroll
  for (int nt = 0; nt < 2; ++nt) {
    const int nl = wn + nt * 16 + col;
    const float bb = nt ? bias1 : bias0;
#pragma unroll
    for (int reg = 0; reg < 4; ++reg) {
      const int ml = wm + quad * 4 + reg;
      epi[nl * 65 + ml] = acc[nt][reg] + bb;
    }
  }
  __syncthreads();

  if (t < 256) {
    float cn[4], hn[4];
#pragma unroll
    for (int jj = 0; jj < 4; ++jj) {
      const int nl = (jl4 + jj) * 4;
      const float gi = epi[(nl + 0) * 65 + mloc];
      const float gf = epi[(nl + 1) * 65 + mloc];
      const float gg = epi[(nl + 2) * 65 + mloc];
      const float go = epi[(nl + 3) * 65 + mloc];
      const float cc = (jj == 0) ? cold.x : (jj == 1) ? cold.y : (jj == 2) ? cold.z : cold.w;
      const float cnew = sigf(gf) * cc + sigf(gi) * tanhfast(gg);
      cn[jj] = cnew;
      hn[jj] = sigf(go) * tanhfast(cnew);
    }
    *(float4*)(cst + (size_t)(m0 + mloc) * HIDDEN + (j0 + jl4)) =
        make_float4(cn[0], cn[1], cn[2], cn[3]);
    ushort4 uh, ul;
    uh.x = bf16_rne(hn[0]); uh.y = bf16_rne(hn[1]);
    uh.z = bf16_rne(hn[2]); uh.w = bf16_rne(hn[3]);
    ul.x = bf16_rne(hn[0] - bf16f(uh.x));
    ul.y = bf16_rne(hn[1] - bf16f(uh.y));
    ul.z = bf16_rne(hn[2] - bf16f(uh.z));
    ul.w = bf16_rne(hn[3] - bf16f(uh.w));
    *(ushort4*)(h_hi_w + (size_t)(m0 + mloc) * HIDDEN + (j0 + jl4)) = uh;
    *(ushort4*)(h_lo_w + (size_t)(m0 + mloc) * HIDDEN + (j0 + jl4)) = ul;
  }
}

// ---------------- head GEMM: z = h @ W1^T + b1 (64x64 LDS pipelined, 3-MFMA) ----------------
__global__ __launch_bounds__(256) void head_gemm(
    const unsigned short* __restrict__ Ah_,     // h_hi [256][1024]
    const unsigned short* __restrict__ Al_,
    const unsigned short* __restrict__ Bh_,     // W1 hi [1024][1024]
    const unsigned short* __restrict__ Bl_,
    const float* __restrict__ bias,
    float* __restrict__ C)                      // z [256][1024]
{
  __shared__ short sb[2 * 4 * 2560];

  const int t    = threadIdx.x;
  const int lane = t & 63;
  const int wave = t >> 6;
  const int wm   = (wave >> 1) * 32;
  const int wn   = (wave & 1) * 32;
  const int col  = lane & 15;
  const int quad = lane >> 4;
  const int r    = t >> 2;
  const int k8   = (t & 3) * 8;
  const int m0   = blockIdx.y * 64;
  const int n0   = blockIdx.x * 64;

#define LOAD_TILE(kt, AH, AL, BH, BL) do {                                   \
    const int ka = (kt) * 32 + k8;                                           \
    AH = *(const uint4*)(Ah_ + (size_t)(m0 + r) * KH + ka);                  \
    AL = *(const uint4*)(Al_ + (size_t)(m0 + r) * KH + ka);                  \
    BH = *(const uint4*)(Bh_ + (size_t)(n0 + r) * KH + ka);                  \
    BL = *(const uint4*)(Bl_ + (size_t)(n0 + r) * KH + ka);                  \
  } while (0)

#define STORE_TILE(base, AH, AL, BH, BL) do {                                \
    *(uint4*)((base) +        r * 40 + k8) = AH;                             \
    *(uint4*)((base) + 2560 + r * 40 + k8) = AL;                             \
    *(uint4*)((base) + 5120 + r * 40 + k8) = BH;                             \
    *(uint4*)((base) + 7680 + r * 40 + k8) = BL;                             \
  } while (0)

  floatx4 acc[2][2];
#pragma unroll
  for (int i = 0; i < 2; ++i)
#pragma unroll
    for (int jj = 0; jj < 2; ++jj)
      acc[i][jj] = (floatx4){0.f, 0.f, 0.f, 0.f};

  uint4 cAh, cAl, cBh, cBl, nAh, nAl, nBh, nBl, tAh, tAl, tBh, tBl;
  LOAD_TILE(0, tAh, tAl, tBh, tBl);
  LOAD_TILE(1, cAh, cAl, cBh, cBl);
  STORE_TILE(sb, tAh, tAl, tBh, tBl);

  for (int kt = 0; kt < NKTH; ++kt) {
    if (kt + 2 < NKTH) LOAD_TILE(kt + 2, nAh, nAl, nBh, nBl);
    __syncthreads();
    short* bufp = sb + (kt & 1) * 10240;

    short8 ah[2], al[2], bh[2], bl[2];
#pragma unroll
    for (int mt = 0; mt < 2; ++mt) {
      const int row = (wm + mt * 16 + col) * 40 + quad * 8;
      ah[mt] = *(const short8*)(bufp + row);
      al[mt] = *(const short8*)(bufp + 2560 + row);
    }
#pragma unroll
    for (int nt = 0; nt < 2; ++nt) {
      const int row = (wn + nt * 16 + col) * 40 + quad * 8;
      bh[nt] = *(const short8*)(bufp + 5120 + row);
      bl[nt] = *(const short8*)(bufp + 7680 + row);
    }
#pragma unroll
    for (int mt = 0; mt < 2; ++mt)
#pragma unroll
      for (int nt = 0; nt < 2; ++nt)
        mfma3(acc[mt][nt], ah[mt], al[mt], bh[nt], bl[nt]);

    if (kt + 1 < NKTH) STORE_TILE(sb + ((kt + 1) & 1) * 10240, cAh, cAl, cBh, cBl);
    cAh = nAh; cAl = nAl; cBh = nBh; cBl = nBl;
  }
#undef LOAD_TILE
#undef STORE_TILE

#pragma unroll
  for (int mt = 0; mt < 2; ++mt)
#pragma unroll
    for (int nt = 0; nt < 2; ++nt) {
      const int nl = n0 + wn + nt * 16 + col;
      const float bb = bias[nl];
#pragma unroll
      for (int reg = 0; reg < 4; ++reg) {
        const int ml = m0 + wm + mt * 16 + quad * 4 + reg;
        C[(size_t)ml * LINEARN + nl] = acc[mt][nt][reg] + bb;
      }
    }
}

// ---------------- BN stats ----------------
__global__ __launch_bounds__(64) void bn_stats(
    const float* __restrict__ z, float* __restrict__ mean, float* __restrict__ rstd)
{
  const int n = blockIdx.x;
  const int t = threadIdx.x;
  float s = 0.f, s2 = 0.f;
  for (int r = t; r < BATCH; r += 64) {
    const float v = z[(size_t)r * LINEARN + n];
    s += v; s2 += v * v;
  }
#pragma unroll
  for (int off = 32; off > 0; off >>= 1) {
    s  += __shfl_down(s,  off, 64);
    s2 += __shfl_down(s2, off, 64);
  }
  if (t == 0) {
    const float mm = s * (1.f / BATCH);
    mean[n] = mm;
    rstd[n] = rsqrtf(s2 * (1.f / BATCH) - mm * mm + 1e-5f);
  }
}

// ---------------- head out ----------------
__global__ __launch_bounds__(256) void head_out(
    const float* __restrict__ z, const float* __restrict__ mean, const float* __restrict__ rstd,
    const float* __restrict__ gamma, const float* __restrict__ beta,
    const float* __restrict__ W2, const float* __restrict__ b2, float* __restrict__ out)
{
  const int b = blockIdx.x;
  const int t = threadIdx.x;
  float acc = 0.f;
  for (int n = t; n < LINEARN; n += 256) {
    float v = (z[(size_t)b * LINEARN + n] - mean[n]) * rstd[n] * gamma[n] + beta[n];
    v = fmaxf(v, 0.f);
    acc += v * W2[n];
  }
#pragma unroll
  for (int off = 32; off > 0; off >>= 1) acc += __shfl_down(acc, off, 64);
  __shared__ float ls[4];
  if ((t & 63) == 0) ls[t >> 6] = acc;
  __syncthreads();
  if (t == 0) {
    const float tot = ls[0] + ls[1] + ls[2] + ls[3] + b2[0];
    out[b] = 3.f / (1.f + __expf(-tot));
  }
}

// ---------------- launch ----------------
extern "C" void kernel_launch(void* const* d_in, const int* in_sizes, int n_in,
                              void* d_out, int out_size, void* d_ws, size_t ws_size,
                              hipStream_t stream) {
  const float* x     = (const float*)d_in[0];
  const float* W_ih  = (const float*)d_in[1];
  const float* W_hh  = (const float*)d_in[2];
  const float* b_ih  = (const float*)d_in[3];
  const float* b_hh  = (const float*)d_in[4];
  const float* W1    = (const float*)d_in[5];
  const float* b1    = (const float*)d_in[6];
  const float* gamma = (const float*)d_in[7];
  const float* beta  = (const float*)d_in[8];
  const float* W2    = (const float*)d_in[9];
  const float* b2    = (const float*)d_in[10];
  float* out = (float*)d_out;
  char* w = (char*)d_ws;

  // persistent-path layout
  const size_t HB_OFF   = 0;                     // 65 x 1MB = 68,157,440
  const size_t BARC_OFF = 68157440;              // 8 KB (two 4KB phase regions)
  const size_t CST_OFF  = 68165632;              // 1 MB
  const size_t WPH_OFF  = 69214208;              // 11,534,336
  const size_t BIAS_OFF = 80748544;              // 16 KB
  const size_t XPH_OFF  = 80764928;              // 25,165,824
  const size_t XPL_OFF  = 105930752;             // 25,165,824
  const size_t W1PH_OFF = 131096576;             // 2 MB
  const size_t W1PL_OFF = 133193728;             // 2 MB
  const size_t Z_OFF    = 135290880;             // 1 MB
  const size_t MEAN_OFF = 136339456;
  const size_t RSTD_OFF = 136343552;
  const size_t NEED     = 136347648;

  if (ws_size >= NEED) {
    unsigned short* Wph   = (unsigned short*)(w + WPH_OFF);
    float*          biasp = (float*)(w + BIAS_OFF);
    unsigned short* xph   = (unsigned short*)(w + XPH_OFF);
    unsigned short* xpl   = (unsigned short*)(w + XPL_OFF);
    unsigned short* W1ph  = (unsigned short*)(w + W1PH_OFF);
    unsigned short* W1pl  = (unsigned short*)(w + W1PL_OFF);
    float*          cst   = (float*)(w + CST_OFF);
    float*          z     = (float*)(w + Z_OFF);
    float*          mean  = (float*)(w + MEAN_OFF);
    float*          rstd  = (float*)(w + RSTD_OFF);
    unsigned int*   barcA = (unsigned int*)(w + BARC_OFF);
    unsigned int*   barcB = barcA + 1024;

    zero_ws<<<256, 256, 0, stream>>>((float4*)(w + HB_OFF), 65536);   // h[0] = 0
    zero_ws<<<2, 256, 0, stream>>>((float4*)(w + BARC_OFF), 512);     // both barrier regions
    pack_w<<<(NG * KT + 255) / 256, 256, 0, stream>>>(W_ih, W_hh, Wph);
    pack_bias<<<NG / 256, 256, 0, stream>>>(b_ih, b_hh, biasp);
    pack_x<<<(SEQ * BATCH * KXP + 255) / 256, 256, 0, stream>>>(x, xph, xpl);
    pack_w1<<<(LINEARN * HIDDEN + 255) / 256, 256, 0, stream>>>(W1, W1ph, W1pl);

    lstm_persist4<<<256, 512, 0, stream>>>(xph, xpl, Wph, biasp, w + HB_OFF, barcA, cst, 0);
    lstm_persist4<<<256, 512, 0, stream>>>(xph, xpl, Wph, biasp, w + HB_OFF, barcB, cst, 1);

    // final h (global step 128) = phase-1 local s=63 -> buffer 63
    const unsigned short* hfh = (const unsigned short*)(w + HB_OFF + (size_t)63 * HBSTEP);
    const unsigned short* hfl = hfh + 262144;
    head_gemm<<<dim3(LINEARN / 64, BATCH / 64), 256, 0, stream>>>(
        hfh, hfl, W1ph, W1pl, b1, z);
    bn_stats<<<LINEARN, 64, 0, stream>>>(z, mean, rstd);
    head_out<<<BATCH, 256, 0, stream>>>(z, mean, rstd, gamma, beta, W2, b2, out);
  } else {
    // -------- fallback: R9-verified 128-launch path --------
    unsigned short* h_hi0 = (unsigned short*)(w + 0);
    unsigned short* h_lo0 = (unsigned short*)(w + 524288);
    float*          cst   = (float*)(w + 1048576);
    unsigned short* h_hi1 = (unsigned short*)(w + 2097152);
    unsigned short* h_lo1 = (unsigned short*)(w + 2621440);
    unsigned short* Wph   = (unsigned short*)(w + 3145728);
    float*          biasp = (float*)(w + 14680064);
    unsigned short* xph   = (unsigned short*)(w + 14696448);
    unsigned short* xpl   = (unsigned short*)(w + 39862272);
    unsigned short* W1ph  = (unsigned short*)(w + 65028096);
    unsigned short* W1pl  = (unsigned short*)(w + 67125248);
    float*          z     = (float*)(w + 69222400);
    float*          mean  = (float*)(w + 70270976);
    float*          rstd  = (float*)(w + 70275072);

    zero_ws<<<512, 256, 0, stream>>>((float4*)w, 131072);
    pack_w<<<(NG * KT + 255) / 256, 256, 0, stream>>>(W_ih, W_hh, Wph);
    pack_bias<<<NG / 256, 256, 0, stream>>>(b_ih, b_hh, biasp);
    pack_x<<<(SEQ * BATCH * KXP + 255) / 256, 256, 0, stream>>>(x, xph, xpl);
    pack_w1<<<(LINEARN * HIDDEN + 255) / 256, 256, 0, stream>>>(W1, W1ph, W1pl);

    for (int t = 0; t < SEQ; ++t) {
      const unsigned short* hr_hi = (t & 1) ? h_hi1 : h_hi0;
      const unsigned short* hr_lo = (t & 1) ? h_lo1 : h_lo0;
      unsigned short* hw_hi = (t & 1) ? h_hi0 : h_hi1;
      unsigned short* hw_lo = (t & 1) ? h_lo0 : h_lo1;
      lstm_step6<<<256, 512, 0, stream>>>(
          xph + (size_t)t * BATCH * KXP, xpl + (size_t)t * BATCH * KXP,
          hr_hi, hr_lo, Wph, biasp, cst, hw_hi, hw_lo);
    }
    head_gemm<<<dim3(LINEARN / 64, BATCH / 64), 256, 0, stream>>>(
        h_hi0, h_lo0, W1ph, W1pl, b1, z);
    bn_stats<<<LINEARN, 64, 0, stream>>>(z, mean, rstd);
    head_out<<<BATCH, 256, 0, stream>>>(z, mean, rstd, gamma, beta, W2, b2, out);
  }
}